// Round 9
// baseline (413.448 us; speedup 1.0000x reference)
//
#include <hip/hip_runtime.h>
#include <stdint.h>

// R15: R14 + register-pressure cap on the fused-RoPE GEMMs.
//   R14 post-mortem: fused epilogue raised VGPR to 120 -> only 4 of 6
//   blocks/CU resident (occ 21%, MfmaUtil 31 vs 38.7 unfused). Main loop
//   needs only 84 VGPR (R12 measurement, identical structure).
//   __launch_bounds__(256, 6) caps VGPR at 512/6=85: main loop allocates
//   as in R12; any epilogue overflow spills once per kernel (epilogue-local),
//   not per K-iteration. Applied to qkv_gemm + proj_gemm.
//   Everything else byte-identical to R14 (B-col remap, in-register RoPE
//   pairs, attn pairing fix, verified inner loops).

typedef unsigned short u16;
typedef unsigned int u32;
typedef __attribute__((ext_vector_type(8))) short bf16x8;
typedef __attribute__((ext_vector_type(4))) float f32x4;

#define SEQ 2048
#define DM 2048
#define NH 16
#define HD 128
#define SM_SCALE 0.08838834764831845f
#define K2LOG 0.12751743f   // SM_SCALE * log2(e)

__device__ __forceinline__ u16 f2bf(float f) {
  union { float f; uint32_t u; } v; v.f = f;
  uint32_t u = v.u + 0x7fffu + ((v.u >> 16) & 1u);   // RNE
  return (u16)(u >> 16);
}
__device__ __forceinline__ float bf2f(u16 h) {
  union { uint32_t u; float f; } v; v.u = ((uint32_t)h) << 16; return v.f;
}
__device__ __forceinline__ u32 pack2(float a, float b) {
  return (u32)f2bf(a) | ((u32)f2bf(b) << 16);
}
__device__ __forceinline__ u32 pack2_trunc(float a, float b) {   // RTZ: P in [0,1]
  union { float f; u32 u; } x, y; x.f = a; y.f = b;
  return (x.u >> 16) | (y.u & 0xFFFF0000u);
}

// async global->LDS, 16B per lane; LDS dest = wave-uniform base + lane*16 (HW)
__device__ __forceinline__ void gl2lds16(const void* g, void* l) {
  __builtin_amdgcn_global_load_lds(
      (const __attribute__((address_space(1))) uint32_t*)g,
      (__attribute__((address_space(3))) uint32_t*)l, 16, 0, 0);
}

// ---------------- elementwise fp32 -> bf16 of x ----------------
__global__ __launch_bounds__(256) void cvt_x(const float* __restrict__ x, u16* __restrict__ xb) {
  int i = blockIdx.x * 256 + threadIdx.x;
  float4 v = ((const float4*)x)[i];
  uint2 r;
  r.x = pack2(v.x, v.y);
  r.y = pack2(v.z, v.w);
  ((uint2*)xb)[i] = r;
}

// ---------------- W (K,N) fp32 -> Wt (N,K) bf16, tiled transpose ----------------
__global__ __launch_bounds__(256) void wtrans(const float* __restrict__ w0, const float* __restrict__ w1,
                                              const float* __restrict__ w2, const float* __restrict__ w3,
                                              u16* __restrict__ dst) {
  const float* W = blockIdx.z == 0 ? w0 : blockIdx.z == 1 ? w1 : blockIdx.z == 2 ? w2 : w3;
  u16* D = dst + (size_t)blockIdx.z * DM * DM;
  int k0 = blockIdx.x * 32, n0 = blockIdx.y * 32;
  __shared__ u16 t[32][33];
  int tx = threadIdx.x, ty = threadIdx.y;   // (32,8)
#pragma unroll
  for (int i = 0; i < 32; i += 8)
    t[ty + i][tx] = f2bf(W[(size_t)(k0 + ty + i) * DM + n0 + tx]);
  __syncthreads();
#pragma unroll
  for (int i = 0; i < 32; i += 8)
    D[(size_t)(n0 + ty + i) * DM + k0 + tx] = t[tx][ty + i];
}

// ---------------- 128x128 (BK=64) bf16 MFMA GEMM core (R9 verified structure) ----------------
// B columns per wave: colOf(nt) = (wave&1)*32 + (nt&1)*16 + (nt>>1)*64
// (RoPE pairs nt and nt+2 land in the same thread; bijective over 128 cols).
__device__ __forceinline__ void gemm_core(const u16* __restrict__ A, const u16* __restrict__ Bt,
                                          int m0, int n0, u16* As, u16* Bs, f32x4 acc[4][4]) {
  int tid = threadIdx.x, lane = tid & 63;
  int l15 = lane & 15, quad = lane >> 4;
  int wave = tid >> 6;
  int wm = (wave >> 1) * 64, wn2 = wave & 1;
  for (int k0 = 0; k0 < DM; k0 += 64) {
#pragma unroll
    for (int i = 0; i < 4; ++i) {
      int s = i * 256 + tid;
      int row = s >> 3, c = (s & 7) ^ (row & 7);
      gl2lds16(&A[(size_t)(m0 + row) * DM + k0 + c * 8], &As[(s & ~63) * 8]);
      gl2lds16(&Bt[(size_t)(n0 + row) * DM + k0 + c * 8], &Bs[(s & ~63) * 8]);
    }
    __syncthreads();
#pragma unroll
    for (int kk = 0; kk < 2; ++kk) {
      bf16x8 af[4], bfr[4];
#pragma unroll
      for (int mt = 0; mt < 4; ++mt) {
        int row = wm + mt * 16 + l15;
        int c = (kk * 4 + quad) ^ (row & 7);
        af[mt] = *(const bf16x8*)&As[row * 64 + c * 8];
      }
#pragma unroll
      for (int nt = 0; nt < 4; ++nt) {
        int row = wn2 * 32 + (nt & 1) * 16 + (nt >> 1) * 64 + l15;
        int c = (kk * 4 + quad) ^ (row & 7);
        bfr[nt] = *(const bf16x8*)&Bs[row * 64 + c * 8];
      }
#pragma unroll
      for (int mt = 0; mt < 4; ++mt)
#pragma unroll
        for (int nt = 0; nt < 4; ++nt)
          acc[mt][nt] = __builtin_amdgcn_mfma_f32_16x16x32_bf16(af[mt], bfr[nt], acc[mt][nt], 0, 0, 0);
    }
    __syncthreads();
  }
}

// z=0 -> Q (rope'd), z=1 -> K (rope'd), z=2 -> V stored TRANSPOSED into Vt (b,h,d,s)
__global__ __launch_bounds__(256, 6) void qkv_gemm(const u16* __restrict__ X, const u16* __restrict__ Wt,
                                                   const int* __restrict__ pos,
                                                   u16* __restrict__ Qo, u16* __restrict__ Ko,
                                                   u16* __restrict__ Vto) {
  __shared__ u16 As[128 * 64];
  __shared__ u16 Bs[128 * 64];
  const u16* Bt = Wt + (size_t)blockIdx.z * DM * DM;
  int n0 = blockIdx.x * 128, m0 = blockIdx.y * 128;
  f32x4 acc[4][4] = {};
  gemm_core(X, Bt, m0, n0, As, Bs, acc);
  int lane = threadIdx.x & 63, wave = threadIdx.x >> 6;
  int l15 = lane & 15, quad = lane >> 4;
  int wm = (wave >> 1) * 64, wn2 = wave & 1;
  if (blockIdx.z == 2) {
    int h = n0 >> 7;
#pragma unroll
    for (int mt = 0; mt < 4; ++mt)
#pragma unroll
      for (int nt = 0; nt < 4; ++nt) {
        int tok = m0 + wm + mt * 16 + quad * 4;
        int d = wn2 * 32 + (nt & 1) * 16 + (nt >> 1) * 64 + l15;
        int b = tok >> 11, sx = tok & (SEQ - 1);
        u16* dp = &Vto[((size_t)(b * NH + h) * HD + d) * SEQ + sx];
        *(u32*)&dp[0] = pack2(acc[mt][nt][0], acc[mt][nt][1]);
        *(u32*)&dp[2] = pack2(acc[mt][nt][2], acc[mt][nt][3]);
      }
  } else {
    // ---- fused RoPE epilogue, in-register pairs (np, np+2) = (i, i+64) ----
    u16* C = blockIdx.z == 0 ? Qo : Ko;
    float invrev[2];
    int iv[2];
#pragma unroll
    for (int np = 0; np < 2; ++np) {
      iv[np] = wn2 * 32 + np * 16 + l15;                 // i in [0,64)
      invrev[np] = exp2f(fmaf((float)iv[np], -0.20762051f, -2.6514961f));
    }
#pragma unroll
    for (int mt = 0; mt < 4; ++mt)
#pragma unroll
      for (int r = 0; r < 4; ++r) {
        int tok = m0 + wm + mt * 16 + quad * 4 + r;
        int b = tok >> 11, sx = tok & (SEQ - 1);
        float pf = (float)pos[b * SEQ + sx];
        u16* cp = &C[(size_t)tok * DM + n0];
#pragma unroll
        for (int np = 0; np < 2; ++np) {
          float hv = pf * invrev[np];
          float err = fmaf(pf, invrev[np], -hv);
          float fr = (hv - truncf(hv)) + err;
          float ang = fr * 6.2831853f;
          float sn = __sinf(ang), cs = __cosf(ang);
          float own = acc[mt][np][r];        // col = iv[np]      (first half)
          float par = acc[mt][np + 2][r];    // col = iv[np] + 64 (second half)
          cp[iv[np]]      = f2bf(own * cs - par * sn);
          cp[iv[np] + 64] = f2bf(fmaf(par, cs, own * sn));
        }
      }
  }
}

__global__ __launch_bounds__(256, 6) void proj_gemm(const u16* __restrict__ A, const u16* __restrict__ Wt,
                                                    float* __restrict__ C) {
  __shared__ u16 As[128 * 64];
  __shared__ u16 Bs[128 * 64];
  int n0 = blockIdx.x * 128, m0 = blockIdx.y * 128;
  f32x4 acc[4][4] = {};
  gemm_core(A, Wt, m0, n0, As, Bs, acc);
  int lane = threadIdx.x & 63, wave = threadIdx.x >> 6;
  int l15 = lane & 15, quad = lane >> 4;
  int wm = (wave >> 1) * 64, wn2 = wave & 1;
#pragma unroll
  for (int mt = 0; mt < 4; ++mt)
#pragma unroll
    for (int nt = 0; nt < 4; ++nt) {
      int col = wn2 * 32 + (nt & 1) * 16 + (nt >> 1) * 64 + l15;
#pragma unroll
      for (int r = 0; r < 4; ++r)
        C[(size_t)(m0 + wm + mt * 16 + quad * 4 + r) * DM + n0 + col] = acc[mt][nt][r];
    }
}

// ---------------- Flash attention: LDS-shared K/V, 4 stripes of one (b,h) per block --------
// Co-resident pair on a CU is (bx, bx+256) -> (g4, g4+8). Map g = g4<8 ? g4 : 23-g4
// pairs (a, 15-a): per-CU tile total constant.  (R13 verified, -15us)
__global__ __launch_bounds__(256, 2) void attn_k(const u16* __restrict__ Q, const u16* __restrict__ K,
                                                 const u16* __restrict__ Vt, const int* __restrict__ pos,
                                                 u16* __restrict__ AO) {
  __shared__ u16 Ks[2][64 * 128];    // 16 KB per buffer
  __shared__ u16 Vs[2][128 * 64];    // 16 KB per buffer
  int tid = threadIdx.x, lane = tid & 63, wave = tid >> 6;
  int bx = blockIdx.x;
  int bh = bx & 31;
  int g4 = bx >> 5;                          // 0..15
  int g = (g4 < 8) ? g4 : (23 - g4);         // pairs (a, 15-a) across bx/bx+256
  int b = bh >> 4, h = bh & 15;
  int stripe = 4 * g + wave;                 // 0..63
  int l15 = lane & 15, quad = lane >> 4;
  const int* posb = pos + b * SEQ;
  int qbase = stripe * 32;
  const u16* Kg = &K[(size_t)(b * SEQ) * DM + h * HD];
  const u16* Vg = &Vt[(size_t)(b * NH + h) * HD * SEQ];

  bf16x8 qf[2][4];
#pragma unroll
  for (int qi = 0; qi < 2; ++qi)
#pragma unroll
    for (int kk = 0; kk < 4; ++kk)
      qf[qi][kk] = *(const bf16x8*)&Q[(size_t)(b * SEQ + qbase + qi * 16 + l15) * DM
                                      + h * HD + kk * 32 + quad * 8];

  auto ub = [&](int v) {
    int c = 0;
#pragma unroll
    for (int st = 1024; st; st >>= 1)
      if (posb[c + st - 1] <= v) c += st;
    if (c == 2047 && posb[2047] <= v) c = 2048;
    return c;
  };
  int cnt[2];
  cnt[0] = ub(posb[qbase + l15]);
  cnt[1] = ub(posb[qbase + 16 + l15]);
  int cnt_min = ub(posb[qbase]);
  int cnt_max = ub(posb[qbase + 31]);
  int ntile = (cnt_max + 63) >> 6;
  int cnt_blk = ub(posb[(4 * g + 3) * 32 + 31]);
  int ntile_blk = (cnt_blk + 63) >> 6;

  auto STAGE = [&](int j0, int bufi) {
#pragma unroll
    for (int i = 0; i < 4; ++i) {
      int s = i * 256 + tid;
      int rk = s >> 4, ck = (s & 15) ^ (rk & 15);
      gl2lds16(&Kg[(size_t)(j0 + rk) * DM + ck * 8], &Ks[bufi][(s & ~63) * 8]);
      int rv = s >> 3, cv = (s & 7) ^ (rv & 7);
      gl2lds16(&Vg[(size_t)rv * SEQ + j0 + cv * 8], &Vs[bufi][(s & ~63) * 8]);
    }
  };

  STAGE(0, 0);
  __syncthreads();

  float m_i[2] = {-1.0e30f, -1.0e30f}, l_i[2] = {0.0f, 0.0f};
  f32x4 oacc[2][8] = {};

  int base0 = l15 + ((quad & 1) << 5);
  bool hi_sel = (quad >> 1) != 0;

  for (int j = 0; j < ntile_blk; ++j) {
    int cur = j & 1;
    if (j + 1 < ntile_blk) STAGE((j + 1) * 64, cur ^ 1);

    if (j < ntile) {
      int j0 = j * 64;
      f32x4 sacc[2][4] = {};
#pragma unroll
      for (int kt = 0; kt < 4; ++kt) {
        bf16x8 kfa[4];
#pragma unroll
        for (int kk = 0; kk < 4; ++kk) {
          int cs = (kk * 4 + quad) ^ l15;
          kfa[kk] = *(const bf16x8*)&Ks[cur][((kt * 16 + l15) * 16 + cs) * 8];
        }
#pragma unroll
        for (int qi = 0; qi < 2; ++qi)
#pragma unroll
          for (int kk = 0; kk < 4; ++kk)
            sacc[qi][kt] = __builtin_amdgcn_mfma_f32_16x16x32_bf16(kfa[kk], qf[qi][kk], sacc[qi][kt], 0, 0, 0);
      }

      bool need_mask = (j0 + 64 > cnt_min);
      u32 pb[2][4][2];
#pragma unroll
      for (int qi = 0; qi < 2; ++qi) {
        if (need_mask) {
          int rel = cnt[qi] - j0;
#pragma unroll
          for (int kt = 0; kt < 4; ++kt)
#pragma unroll
            for (int r = 0; r < 4; ++r)
              if (kt * 16 + quad * 4 + r >= rel) sacc[qi][kt][r] = -1.0e30f;
        }
        float mx = fmaxf(fmaxf(sacc[qi][0][0], sacc[qi][0][1]), fmaxf(sacc[qi][0][2], sacc[qi][0][3]));
#pragma unroll
        for (int kt = 1; kt < 4; ++kt)
          mx = fmaxf(mx, fmaxf(fmaxf(sacc[qi][kt][0], sacc[qi][kt][1]),
                               fmaxf(sacc[qi][kt][2], sacc[qi][kt][3])));
        mx = fmaxf(mx, __shfl_xor(mx, 16));
        mx = fmaxf(mx, __shfl_xor(mx, 32));
        float mold = m_i[qi];
        float mn = fmaxf(mold, mx);
        if (__any(mn > mold)) {
          float al = exp2f((mold - mn) * K2LOG);
          l_i[qi] *= al;
#pragma unroll
          for (int dt = 0; dt < 8; ++dt) oacc[qi][dt] *= al;
          m_i[qi] = mn;
        }
        float nc = -m_i[qi] * K2LOG;
        float rs = 0.0f;
#pragma unroll
        for (int kt = 0; kt < 4; ++kt) {
          float p0 = exp2f(fmaf(sacc[qi][kt][0], K2LOG, nc));
          float p1 = exp2f(fmaf(sacc[qi][kt][1], K2LOG, nc));
          float p2 = exp2f(fmaf(sacc[qi][kt][2], K2LOG, nc));
          float p3 = exp2f(fmaf(sacc[qi][kt][3], K2LOG, nc));
          rs += (p0 + p1) + (p2 + p3);
          pb[qi][kt][0] = pack2_trunc(p0, p1);
          pb[qi][kt][1] = pack2_trunc(p2, p3);
        }
        rs += __shfl_xor(rs, 16);
        rs += __shfl_xor(rs, 32);
        l_i[qi] += rs;
      }

#pragma unroll
      for (int kk2 = 0; kk2 < 2; ++kk2) {
        bf16x8 vf[8];
#pragma unroll
        for (int dt = 0; dt < 8; ++dt) {
          int cs = (kk2 * 4 + quad) ^ (l15 & 7);
          vf[dt] = *(const bf16x8*)&Vs[cur][((dt * 16 + l15) * 8 + cs) * 8];
        }
#pragma unroll
        for (int qi = 0; qi < 2; ++qi) {
          u32 wv[4];
#pragma unroll
          for (int wd = 0; wd < 4; ++wd) {
            int src = base0 + ((wd >> 1) << 4);
            u32 va = __shfl(pb[qi][kk2 * 2 + 0][wd & 1], src);
            u32 vb = __shfl(pb[qi][kk2 * 2 + 1][wd & 1], src);
            wv[wd] = hi_sel ? vb : va;
          }
          union { bf16x8 v; u32 u[4]; } pt;
          pt.u[0] = wv[0]; pt.u[1] = wv[1]; pt.u[2] = wv[2]; pt.u[3] = wv[3];
#pragma unroll
          for (int dt = 0; dt < 8; ++dt)
            oacc[qi][dt] = __builtin_amdgcn_mfma_f32_16x16x32_bf16(vf[dt], pt.v, oacc[qi][dt], 0, 0, 0);
        }
      }
    }
    __syncthreads();
  }

#pragma unroll
  for (int qi = 0; qi < 2; ++qi) {
    float inv = 1.0f / l_i[qi];
    u16* aop = &AO[(size_t)(b * SEQ + qbase + qi * 16 + l15) * DM + h * HD];
#pragma unroll
    for (int dt = 0; dt < 8; ++dt) {
      int col = dt * 16 + quad * 4;
      *(u32*)&aop[col]     = pack2(oacc[qi][dt][0] * inv, oacc[qi][dt][1] * inv);
      *(u32*)&aop[col + 2] = pack2(oacc[qi][dt][2] * inv, oacc[qi][dt][3] * inv);
    }
  }
}

extern "C" void kernel_launch(void* const* d_in, const int* in_sizes, int n_in,
                              void* d_out, int out_size, void* d_ws, size_t ws_size,
                              hipStream_t stream) {
  const float* x  = (const float*)d_in[0];
  const float* Wq = (const float*)d_in[1];
  const float* Wk = (const float*)d_in[2];
  const float* Wv = (const float*)d_in[3];
  const float* Wo = (const float*)d_in[4];
  const int*  pos = (const int*)d_in[5];
  float* out = (float*)d_out;

  u16* ws  = (u16*)d_ws;
  u16* xb  = ws;
  u16* wt  = xb  + (size_t)4096 * 2048;
  u16* qb  = wt  + (size_t)4 * 2048 * 2048;
  u16* kb  = qb  + (size_t)4096 * 2048;
  u16* vtb = kb  + (size_t)4096 * 2048;
  u16* aob = vtb + (size_t)4096 * 2048;

  cvt_x<<<8192, 256, 0, stream>>>(x, xb);
  wtrans<<<dim3(64, 64, 4), dim3(32, 8), 0, stream>>>(Wq, Wk, Wv, Wo, wt);
  qkv_gemm<<<dim3(16, 32, 3), 256, 0, stream>>>(xb, wt, pos, qb, kb, vtb);
  attn_k<<<dim3(512), 256, 0, stream>>>(qb, kb, vtb, pos, aob);
  proj_gemm<<<dim3(16, 32), 256, 0, stream>>>(aob, wt + (size_t)3 * 2048 * 2048, out);
}

// Round 10
// 405.067 us; speedup vs baseline: 1.0207x; 1.0207x over previous
//
#include <hip/hip_runtime.h>
#include <stdint.h>

// R16: R14 fused-RoPE qkv + anti-hoist fence.
//   R13/R14/R15 post-mortem: fused epilogue VGPR 100/120/124 (vs 84 unfused)
//   because ALL epilogue inputs are loop-invariant -- LICM + latency scheduler
//   hoist the 16 pos loads + invrev exp2fs above the 32-iter main loop, keeping
//   them live across every K-step ((256,6) bound was ignored, not honored).
//   Fix: launder the pos pointer through asm volatile AFTER gemm_core -- loads
//   can't be hoisted past the definition of their address. Also: pos reads
//   vectorized (4 consecutive tokens -> one int4; 16 loads -> 4).
//   Plain __launch_bounds__(256). Everything else byte-identical to R14
//   (B-col remap, in-register RoPE pairs, attn pairing fix, verified loops).

typedef unsigned short u16;
typedef unsigned int u32;
typedef __attribute__((ext_vector_type(8))) short bf16x8;
typedef __attribute__((ext_vector_type(4))) float f32x4;

#define SEQ 2048
#define DM 2048
#define NH 16
#define HD 128
#define SM_SCALE 0.08838834764831845f
#define K2LOG 0.12751743f   // SM_SCALE * log2(e)

__device__ __forceinline__ u16 f2bf(float f) {
  union { float f; uint32_t u; } v; v.f = f;
  uint32_t u = v.u + 0x7fffu + ((v.u >> 16) & 1u);   // RNE
  return (u16)(u >> 16);
}
__device__ __forceinline__ float bf2f(u16 h) {
  union { uint32_t u; float f; } v; v.u = ((uint32_t)h) << 16; return v.f;
}
__device__ __forceinline__ u32 pack2(float a, float b) {
  return (u32)f2bf(a) | ((u32)f2bf(b) << 16);
}
__device__ __forceinline__ u32 pack2_trunc(float a, float b) {   // RTZ: P in [0,1]
  union { float f; u32 u; } x, y; x.f = a; y.f = b;
  return (x.u >> 16) | (y.u & 0xFFFF0000u);
}

// async global->LDS, 16B per lane; LDS dest = wave-uniform base + lane*16 (HW)
__device__ __forceinline__ void gl2lds16(const void* g, void* l) {
  __builtin_amdgcn_global_load_lds(
      (const __attribute__((address_space(1))) uint32_t*)g,
      (__attribute__((address_space(3))) uint32_t*)l, 16, 0, 0);
}

// ---------------- elementwise fp32 -> bf16 of x ----------------
__global__ __launch_bounds__(256) void cvt_x(const float* __restrict__ x, u16* __restrict__ xb) {
  int i = blockIdx.x * 256 + threadIdx.x;
  float4 v = ((const float4*)x)[i];
  uint2 r;
  r.x = pack2(v.x, v.y);
  r.y = pack2(v.z, v.w);
  ((uint2*)xb)[i] = r;
}

// ---------------- W (K,N) fp32 -> Wt (N,K) bf16, tiled transpose ----------------
__global__ __launch_bounds__(256) void wtrans(const float* __restrict__ w0, const float* __restrict__ w1,
                                              const float* __restrict__ w2, const float* __restrict__ w3,
                                              u16* __restrict__ dst) {
  const float* W = blockIdx.z == 0 ? w0 : blockIdx.z == 1 ? w1 : blockIdx.z == 2 ? w2 : w3;
  u16* D = dst + (size_t)blockIdx.z * DM * DM;
  int k0 = blockIdx.x * 32, n0 = blockIdx.y * 32;
  __shared__ u16 t[32][33];
  int tx = threadIdx.x, ty = threadIdx.y;   // (32,8)
#pragma unroll
  for (int i = 0; i < 32; i += 8)
    t[ty + i][tx] = f2bf(W[(size_t)(k0 + ty + i) * DM + n0 + tx]);
  __syncthreads();
#pragma unroll
  for (int i = 0; i < 32; i += 8)
    D[(size_t)(n0 + ty + i) * DM + k0 + tx] = t[tx][ty + i];
}

// ---------------- 128x128 (BK=64) bf16 MFMA GEMM core (R9 verified structure) ----------------
// B columns per wave: colOf(nt) = (wave&1)*32 + (nt&1)*16 + (nt>>1)*64
// (RoPE pairs nt and nt+2 land in the same thread; bijective over 128 cols).
__device__ __forceinline__ void gemm_core(const u16* __restrict__ A, const u16* __restrict__ Bt,
                                          int m0, int n0, u16* As, u16* Bs, f32x4 acc[4][4]) {
  int tid = threadIdx.x, lane = tid & 63;
  int l15 = lane & 15, quad = lane >> 4;
  int wave = tid >> 6;
  int wm = (wave >> 1) * 64, wn2 = wave & 1;
  for (int k0 = 0; k0 < DM; k0 += 64) {
#pragma unroll
    for (int i = 0; i < 4; ++i) {
      int s = i * 256 + tid;
      int row = s >> 3, c = (s & 7) ^ (row & 7);
      gl2lds16(&A[(size_t)(m0 + row) * DM + k0 + c * 8], &As[(s & ~63) * 8]);
      gl2lds16(&Bt[(size_t)(n0 + row) * DM + k0 + c * 8], &Bs[(s & ~63) * 8]);
    }
    __syncthreads();
#pragma unroll
    for (int kk = 0; kk < 2; ++kk) {
      bf16x8 af[4], bfr[4];
#pragma unroll
      for (int mt = 0; mt < 4; ++mt) {
        int row = wm + mt * 16 + l15;
        int c = (kk * 4 + quad) ^ (row & 7);
        af[mt] = *(const bf16x8*)&As[row * 64 + c * 8];
      }
#pragma unroll
      for (int nt = 0; nt < 4; ++nt) {
        int row = wn2 * 32 + (nt & 1) * 16 + (nt >> 1) * 64 + l15;
        int c = (kk * 4 + quad) ^ (row & 7);
        bfr[nt] = *(const bf16x8*)&Bs[row * 64 + c * 8];
      }
#pragma unroll
      for (int mt = 0; mt < 4; ++mt)
#pragma unroll
        for (int nt = 0; nt < 4; ++nt)
          acc[mt][nt] = __builtin_amdgcn_mfma_f32_16x16x32_bf16(af[mt], bfr[nt], acc[mt][nt], 0, 0, 0);
    }
    __syncthreads();
  }
}

// z=0 -> Q (rope'd), z=1 -> K (rope'd), z=2 -> V stored TRANSPOSED into Vt (b,h,d,s)
__global__ __launch_bounds__(256) void qkv_gemm(const u16* __restrict__ X, const u16* __restrict__ Wt,
                                                const int* __restrict__ pos,
                                                u16* __restrict__ Qo, u16* __restrict__ Ko,
                                                u16* __restrict__ Vto) {
  __shared__ u16 As[128 * 64];
  __shared__ u16 Bs[128 * 64];
  const u16* Bt = Wt + (size_t)blockIdx.z * DM * DM;
  int n0 = blockIdx.x * 128, m0 = blockIdx.y * 128;
  f32x4 acc[4][4] = {};
  gemm_core(X, Bt, m0, n0, As, Bs, acc);
  int lane = threadIdx.x & 63, wave = threadIdx.x >> 6;
  int l15 = lane & 15, quad = lane >> 4;
  int wm = (wave >> 1) * 64, wn2 = wave & 1;
  if (blockIdx.z == 2) {
    int h = n0 >> 7;
#pragma unroll
    for (int mt = 0; mt < 4; ++mt)
#pragma unroll
      for (int nt = 0; nt < 4; ++nt) {
        int tok = m0 + wm + mt * 16 + quad * 4;
        int d = wn2 * 32 + (nt & 1) * 16 + (nt >> 1) * 64 + l15;
        int b = tok >> 11, sx = tok & (SEQ - 1);
        u16* dp = &Vto[((size_t)(b * NH + h) * HD + d) * SEQ + sx];
        *(u32*)&dp[0] = pack2(acc[mt][nt][0], acc[mt][nt][1]);
        *(u32*)&dp[2] = pack2(acc[mt][nt][2], acc[mt][nt][3]);
      }
  } else {
    // ---- fused RoPE epilogue, in-register pairs (np, np+2) = (i, i+64) ----
    // Anti-hoist fence: pos address becomes "defined" only here, so its loads
    // (and everything derived) cannot be scheduled above the main loop.
    const int* posl = pos;
    asm volatile("" : "+s"(posl));
    u16* C = blockIdx.z == 0 ? Qo : Ko;
    float invrev[2];
    int iv[2];
#pragma unroll
    for (int np = 0; np < 2; ++np) {
      iv[np] = wn2 * 32 + np * 16 + l15;                 // i in [0,64)
      invrev[np] = exp2f(fmaf((float)iv[np], -0.20762051f, -2.6514961f));
    }
#pragma unroll
    for (int mt = 0; mt < 4; ++mt) {
      int tok0 = m0 + wm + mt * 16 + quad * 4;
      int b = tok0 >> 11, sx0 = tok0 & (SEQ - 1);
      int4 pv = *(const int4*)&posl[b * SEQ + sx0];      // 4 consecutive tokens
      int pvr[4] = {pv.x, pv.y, pv.z, pv.w};
#pragma unroll
      for (int r = 0; r < 4; ++r) {
        float pf = (float)pvr[r];
        u16* cp = &C[(size_t)(tok0 + r) * DM + n0];
#pragma unroll
        for (int np = 0; np < 2; ++np) {
          float hv = pf * invrev[np];
          float err = fmaf(pf, invrev[np], -hv);
          float fr = (hv - truncf(hv)) + err;
          float ang = fr * 6.2831853f;
          float sn = __sinf(ang), cs = __cosf(ang);
          float own = acc[mt][np][r];        // col = iv[np]      (first half)
          float par = acc[mt][np + 2][r];    // col = iv[np] + 64 (second half)
          cp[iv[np]]      = f2bf(own * cs - par * sn);
          cp[iv[np] + 64] = f2bf(fmaf(par, cs, own * sn));
        }
      }
    }
  }
}

__global__ __launch_bounds__(256) void proj_gemm(const u16* __restrict__ A, const u16* __restrict__ Wt,
                                                 float* __restrict__ C) {
  __shared__ u16 As[128 * 64];
  __shared__ u16 Bs[128 * 64];
  int n0 = blockIdx.x * 128, m0 = blockIdx.y * 128;
  f32x4 acc[4][4] = {};
  gemm_core(A, Wt, m0, n0, As, Bs, acc);
  int lane = threadIdx.x & 63, wave = threadIdx.x >> 6;
  int l15 = lane & 15, quad = lane >> 4;
  int wm = (wave >> 1) * 64, wn2 = wave & 1;
#pragma unroll
  for (int mt = 0; mt < 4; ++mt)
#pragma unroll
    for (int nt = 0; nt < 4; ++nt) {
      int col = wn2 * 32 + (nt & 1) * 16 + (nt >> 1) * 64 + l15;
#pragma unroll
      for (int r = 0; r < 4; ++r)
        C[(size_t)(m0 + wm + mt * 16 + quad * 4 + r) * DM + n0 + col] = acc[mt][nt][r];
    }
}

// ---------------- Flash attention: LDS-shared K/V, 4 stripes of one (b,h) per block --------
// Co-resident pair on a CU is (bx, bx+256) -> (g4, g4+8). Map g = g4<8 ? g4 : 23-g4
// pairs (a, 15-a): per-CU tile total constant.  (R13 verified, -15us)
__global__ __launch_bounds__(256, 2) void attn_k(const u16* __restrict__ Q, const u16* __restrict__ K,
                                                 const u16* __restrict__ Vt, const int* __restrict__ pos,
                                                 u16* __restrict__ AO) {
  __shared__ u16 Ks[2][64 * 128];    // 16 KB per buffer
  __shared__ u16 Vs[2][128 * 64];    // 16 KB per buffer
  int tid = threadIdx.x, lane = tid & 63, wave = tid >> 6;
  int bx = blockIdx.x;
  int bh = bx & 31;
  int g4 = bx >> 5;                          // 0..15
  int g = (g4 < 8) ? g4 : (23 - g4);         // pairs (a, 15-a) across bx/bx+256
  int b = bh >> 4, h = bh & 15;
  int stripe = 4 * g + wave;                 // 0..63
  int l15 = lane & 15, quad = lane >> 4;
  const int* posb = pos + b * SEQ;
  int qbase = stripe * 32;
  const u16* Kg = &K[(size_t)(b * SEQ) * DM + h * HD];
  const u16* Vg = &Vt[(size_t)(b * NH + h) * HD * SEQ];

  bf16x8 qf[2][4];
#pragma unroll
  for (int qi = 0; qi < 2; ++qi)
#pragma unroll
    for (int kk = 0; kk < 4; ++kk)
      qf[qi][kk] = *(const bf16x8*)&Q[(size_t)(b * SEQ + qbase + qi * 16 + l15) * DM
                                      + h * HD + kk * 32 + quad * 8];

  auto ub = [&](int v) {
    int c = 0;
#pragma unroll
    for (int st = 1024; st; st >>= 1)
      if (posb[c + st - 1] <= v) c += st;
    if (c == 2047 && posb[2047] <= v) c = 2048;
    return c;
  };
  int cnt[2];
  cnt[0] = ub(posb[qbase + l15]);
  cnt[1] = ub(posb[qbase + 16 + l15]);
  int cnt_min = ub(posb[qbase]);
  int cnt_max = ub(posb[qbase + 31]);
  int ntile = (cnt_max + 63) >> 6;
  int cnt_blk = ub(posb[(4 * g + 3) * 32 + 31]);
  int ntile_blk = (cnt_blk + 63) >> 6;

  auto STAGE = [&](int j0, int bufi) {
#pragma unroll
    for (int i = 0; i < 4; ++i) {
      int s = i * 256 + tid;
      int rk = s >> 4, ck = (s & 15) ^ (rk & 15);
      gl2lds16(&Kg[(size_t)(j0 + rk) * DM + ck * 8], &Ks[bufi][(s & ~63) * 8]);
      int rv = s >> 3, cv = (s & 7) ^ (rv & 7);
      gl2lds16(&Vg[(size_t)rv * SEQ + j0 + cv * 8], &Vs[bufi][(s & ~63) * 8]);
    }
  };

  STAGE(0, 0);
  __syncthreads();

  float m_i[2] = {-1.0e30f, -1.0e30f}, l_i[2] = {0.0f, 0.0f};
  f32x4 oacc[2][8] = {};

  int base0 = l15 + ((quad & 1) << 5);
  bool hi_sel = (quad >> 1) != 0;

  for (int j = 0; j < ntile_blk; ++j) {
    int cur = j & 1;
    if (j + 1 < ntile_blk) STAGE((j + 1) * 64, cur ^ 1);

    if (j < ntile) {
      int j0 = j * 64;
      f32x4 sacc[2][4] = {};
#pragma unroll
      for (int kt = 0; kt < 4; ++kt) {
        bf16x8 kfa[4];
#pragma unroll
        for (int kk = 0; kk < 4; ++kk) {
          int cs = (kk * 4 + quad) ^ l15;
          kfa[kk] = *(const bf16x8*)&Ks[cur][((kt * 16 + l15) * 16 + cs) * 8];
        }
#pragma unroll
        for (int qi = 0; qi < 2; ++qi)
#pragma unroll
          for (int kk = 0; kk < 4; ++kk)
            sacc[qi][kt] = __builtin_amdgcn_mfma_f32_16x16x32_bf16(kfa[kk], qf[qi][kk], sacc[qi][kt], 0, 0, 0);
      }

      bool need_mask = (j0 + 64 > cnt_min);
      u32 pb[2][4][2];
#pragma unroll
      for (int qi = 0; qi < 2; ++qi) {
        if (need_mask) {
          int rel = cnt[qi] - j0;
#pragma unroll
          for (int kt = 0; kt < 4; ++kt)
#pragma unroll
            for (int r = 0; r < 4; ++r)
              if (kt * 16 + quad * 4 + r >= rel) sacc[qi][kt][r] = -1.0e30f;
        }
        float mx = fmaxf(fmaxf(sacc[qi][0][0], sacc[qi][0][1]), fmaxf(sacc[qi][0][2], sacc[qi][0][3]));
#pragma unroll
        for (int kt = 1; kt < 4; ++kt)
          mx = fmaxf(mx, fmaxf(fmaxf(sacc[qi][kt][0], sacc[qi][kt][1]),
                               fmaxf(sacc[qi][kt][2], sacc[qi][kt][3])));
        mx = fmaxf(mx, __shfl_xor(mx, 16));
        mx = fmaxf(mx, __shfl_xor(mx, 32));
        float mold = m_i[qi];
        float mn = fmaxf(mold, mx);
        if (__any(mn > mold)) {
          float al = exp2f((mold - mn) * K2LOG);
          l_i[qi] *= al;
#pragma unroll
          for (int dt = 0; dt < 8; ++dt) oacc[qi][dt] *= al;
          m_i[qi] = mn;
        }
        float nc = -m_i[qi] * K2LOG;
        float rs = 0.0f;
#pragma unroll
        for (int kt = 0; kt < 4; ++kt) {
          float p0 = exp2f(fmaf(sacc[qi][kt][0], K2LOG, nc));
          float p1 = exp2f(fmaf(sacc[qi][kt][1], K2LOG, nc));
          float p2 = exp2f(fmaf(sacc[qi][kt][2], K2LOG, nc));
          float p3 = exp2f(fmaf(sacc[qi][kt][3], K2LOG, nc));
          rs += (p0 + p1) + (p2 + p3);
          pb[qi][kt][0] = pack2_trunc(p0, p1);
          pb[qi][kt][1] = pack2_trunc(p2, p3);
        }
        rs += __shfl_xor(rs, 16);
        rs += __shfl_xor(rs, 32);
        l_i[qi] += rs;
      }

#pragma unroll
      for (int kk2 = 0; kk2 < 2; ++kk2) {
        bf16x8 vf[8];
#pragma unroll
        for (int dt = 0; dt < 8; ++dt) {
          int cs = (kk2 * 4 + quad) ^ (l15 & 7);
          vf[dt] = *(const bf16x8*)&Vs[cur][((dt * 16 + l15) * 8 + cs) * 8];
        }
#pragma unroll
        for (int qi = 0; qi < 2; ++qi) {
          u32 wv[4];
#pragma unroll
          for (int wd = 0; wd < 4; ++wd) {
            int src = base0 + ((wd >> 1) << 4);
            u32 va = __shfl(pb[qi][kk2 * 2 + 0][wd & 1], src);
            u32 vb = __shfl(pb[qi][kk2 * 2 + 1][wd & 1], src);
            wv[wd] = hi_sel ? vb : va;
          }
          union { bf16x8 v; u32 u[4]; } pt;
          pt.u[0] = wv[0]; pt.u[1] = wv[1]; pt.u[2] = wv[2]; pt.u[3] = wv[3];
#pragma unroll
          for (int dt = 0; dt < 8; ++dt)
            oacc[qi][dt] = __builtin_amdgcn_mfma_f32_16x16x32_bf16(vf[dt], pt.v, oacc[qi][dt], 0, 0, 0);
        }
      }
    }
    __syncthreads();
  }

#pragma unroll
  for (int qi = 0; qi < 2; ++qi) {
    float inv = 1.0f / l_i[qi];
    u16* aop = &AO[(size_t)(b * SEQ + qbase + qi * 16 + l15) * DM + h * HD];
#pragma unroll
    for (int dt = 0; dt < 8; ++dt) {
      int col = dt * 16 + quad * 4;
      *(u32*)&aop[col]     = pack2(oacc[qi][dt][0] * inv, oacc[qi][dt][1] * inv);
      *(u32*)&aop[col + 2] = pack2(oacc[qi][dt][2] * inv, oacc[qi][dt][3] * inv);
    }
  }
}

extern "C" void kernel_launch(void* const* d_in, const int* in_sizes, int n_in,
                              void* d_out, int out_size, void* d_ws, size_t ws_size,
                              hipStream_t stream) {
  const float* x  = (const float*)d_in[0];
  const float* Wq = (const float*)d_in[1];
  const float* Wk = (const float*)d_in[2];
  const float* Wv = (const float*)d_in[3];
  const float* Wo = (const float*)d_in[4];
  const int*  pos = (const int*)d_in[5];
  float* out = (float*)d_out;

  u16* ws  = (u16*)d_ws;
  u16* xb  = ws;
  u16* wt  = xb  + (size_t)4096 * 2048;
  u16* qb  = wt  + (size_t)4 * 2048 * 2048;
  u16* kb  = qb  + (size_t)4096 * 2048;
  u16* vtb = kb  + (size_t)4096 * 2048;
  u16* aob = vtb + (size_t)4096 * 2048;

  cvt_x<<<8192, 256, 0, stream>>>(x, xb);
  wtrans<<<dim3(64, 64, 4), dim3(32, 8), 0, stream>>>(Wq, Wk, Wv, Wo, wt);
  qkv_gemm<<<dim3(16, 32, 3), 256, 0, stream>>>(xb, wt, pos, qb, kb, vtb);
  attn_k<<<dim3(512), 256, 0, stream>>>(qb, kb, vtb, pos, aob);
  proj_gemm<<<dim3(16, 32), 256, 0, stream>>>(aob, wt + (size_t)3 * 2048 * 2048, out);
}